// Round 8
// baseline (498.866 us; speedup 1.0000x reference)
//
#include <hip/hip_runtime.h>
#include <hip/hip_cooperative_groups.h>

// GCN regressor: 2x (mean-aggregate + linear+ReLU) + per-graph mean + MLP head.
// N=50000 nodes, E=800000 edges, D_IN=128, H1=256, H2=128, G=256.
// R8: all prep (zeroing, count, scan, scatter, gstart, weight transpose+cast,
// h cast) fused into ONE cooperative kernel with grid.sync() phases --
// 17 dispatches -> 6 (launch gap was ~9us/dispatch = ~150us of the R7 total).
// Compute path identical to R7: one-wave-per-node bf16 gather (structural
// floor; chunked variant regressed 7x), bf16 MFMA GEMMs, fused readout.

namespace cg = cooperative_groups;

#define NUM_GRAPHS 256

typedef __attribute__((ext_vector_type(8))) short bf16x8;
typedef __attribute__((ext_vector_type(4))) float f32x4;

__device__ inline unsigned short f2bf(float f) {  // round-to-nearest-even
    unsigned u = __float_as_uint(f);
    return (unsigned short)((u + 0x7fff + ((u >> 16) & 1)) >> 16);
}
__device__ inline float bflo(unsigned u) { return __uint_as_float(u << 16); }
__device__ inline float bfhi(unsigned u) { return __uint_as_float(u & 0xffff0000u); }

// exclusive scan over a 256-thread block; wsum is 8 shared ints; *total = block sum
__device__ inline int block_scan_excl_256(int v, int* wsum, int tid, int* total) {
    int lane = tid & 63, wid = tid >> 6;
    int x = v;
    #pragma unroll
    for (int d = 1; d < 64; d <<= 1) {
        int y = __shfl_up(x, d, 64);
        if (lane >= d) x += y;
    }
    if (lane == 63) wsum[wid] = x;
    __syncthreads();
    if (tid == 0) {
        int run = 0;
        #pragma unroll
        for (int i = 0; i < 4; ++i) { int t = wsum[i]; wsum[i] = run; run += t; }
        wsum[4] = run;
    }
    __syncthreads();
    *total = wsum[4];
    return wsum[wid] + x - v;
}

// ---------------- cooperative prep: zero + count + scan + scatter + gstart +
// weight transpose/cast + h cast. Grid MUST be 256 blocks x 256 threads. ----

__launch_bounds__(256)
__global__ void prep_kernel(const int* __restrict__ src, const int* __restrict__ dst,
                            const int* __restrict__ gids, const float* __restrict__ h,
                            const float* __restrict__ W1, const float* __restrict__ W2,
                            int* __restrict__ cnt, int* __restrict__ offs,
                            int* __restrict__ eidx, int* __restrict__ part,
                            int* __restrict__ gstart, unsigned short* __restrict__ hb,
                            unsigned short* __restrict__ Wt1, unsigned short* __restrict__ Wt2,
                            float* __restrict__ gsum, int N, int E) {
    cg::grid_group grid = cg::this_grid();
    __shared__ int wsum[8];
    int tid = threadIdx.x;
    int gtid = blockIdx.x * 256 + tid;
    int NT = gridDim.x * 256;  // 65536

    // P0: zero cnt, gsum
    for (int i = gtid; i < N; i += NT) cnt[i] = 0;
    for (int i = gtid; i < NUM_GRAPHS * 256; i += NT) gsum[i] = 0.0f;
    grid.sync();

    // P1: degree count (atomics) + independent prep work
    for (int e = gtid; e < E; e += NT) atomicAdd(&cnt[dst[e]], 1);
    for (int n = gtid; n < N; n += NT) {   // graph segment starts (gids sorted)
        int g = gids[n];
        int gp = (n == 0) ? -1 : gids[n - 1];
        for (int x = gp + 1; x <= g; ++x) gstart[x] = n;
        if (n == N - 1)
            for (int x = g + 1; x <= NUM_GRAPHS; ++x) gstart[x] = N;
    }
    for (int i = gtid; i < N * 32; i += NT) {  // cast h -> bf16 (float4 per iter)
        float4 v = *(const float4*)(h + (size_t)i * 4);
        ushort4 o;
        o.x = f2bf(v.x); o.y = f2bf(v.y); o.z = f2bf(v.z); o.w = f2bf(v.w);
        *(ushort4*)(hb + (size_t)i * 4) = o;
    }
    for (int i = gtid; i < 256 * 128; i += NT)  // Wt1[n][k] = bf16(W1[k][n])
        Wt1[i] = f2bf(W1[(size_t)(i & 127) * 256 + (i >> 7)]);
    for (int i = gtid; i < 256 * 256; i += NT)  // Wt2[n][k] = bf16(W2[k][n])
        Wt2[i] = f2bf(W2[(size_t)(i & 255) * 256 + (i >> 8)]);
    grid.sync();

    // P2a: block-local exclusive scan of cnt (<=1 element per thread; NT >= N)
    {
        int v = (gtid < N) ? cnt[gtid] : 0;
        int total;
        int ex = block_scan_excl_256(v, wsum, tid, &total);
        if (gtid < N) offs[gtid] = ex;
        if (tid == 0) part[blockIdx.x] = total;
    }
    grid.sync();

    // P2b: block 0 scans the 256 block totals
    if (blockIdx.x == 0) {
        int v = part[tid];
        int total;
        int ex = block_scan_excl_256(v, wsum, tid, &total);
        part[tid] = ex;
        if (tid == 0) offs[N] = total;
    }
    grid.sync();

    // P2c: add block bases
    if (gtid < N) offs[gtid] += part[blockIdx.x];
    grid.sync();

    // P3: scatter (claim slots by decrementing cnt; cnt dead after this)
    for (int e = gtid; e < E; e += NT) {
        int d = dst[e];
        int p = offs[d] + atomicSub(&cnt[d], 1) - 1;
        eidx[p] = src[e];
    }
}

// ---------------- mean aggregation: one wave per dst node, bf16 gather, fp32 accum ----------------

template <int D>
__global__ void agg_mean_bf16_kernel(const unsigned short* __restrict__ feat,
                                     const int* __restrict__ offs,
                                     const int* __restrict__ eidx,
                                     unsigned short* __restrict__ out, int N) {
    constexpr int VPL = D / 64;  // 2 or 4
    int wave = blockIdx.x * (blockDim.x >> 6) + (threadIdx.x >> 6);
    int lane = threadIdx.x & 63;
    if (wave >= N) return;
    int beg = offs[wave], end = offs[wave + 1];
    float acc[VPL];
    #pragma unroll
    for (int i = 0; i < VPL; ++i) acc[i] = 0.0f;

    int j = beg;
    for (; j + 8 <= end; j += 8) {
        int s[8];
        #pragma unroll
        for (int u = 0; u < 8; ++u) s[u] = eidx[j + u];
        if constexpr (VPL == 2) {
            unsigned v[8];
            #pragma unroll
            for (int u = 0; u < 8; ++u)
                v[u] = *(const unsigned*)(feat + (size_t)s[u] * D + lane * 2);
            #pragma unroll
            for (int u = 0; u < 8; ++u) { acc[0] += bflo(v[u]); acc[1] += bfhi(v[u]); }
        } else {
            uint2 v[8];
            #pragma unroll
            for (int u = 0; u < 8; ++u)
                v[u] = *(const uint2*)(feat + (size_t)s[u] * D + lane * 4);
            #pragma unroll
            for (int u = 0; u < 8; ++u) {
                acc[0] += bflo(v[u].x); acc[1] += bfhi(v[u].x);
                acc[2] += bflo(v[u].y); acc[3] += bfhi(v[u].y);
            }
        }
    }
    for (; j < end; ++j) {
        int s = eidx[j];
        if constexpr (VPL == 2) {
            unsigned v = *(const unsigned*)(feat + (size_t)s * D + lane * 2);
            acc[0] += bflo(v); acc[1] += bfhi(v);
        } else {
            uint2 v = *(const uint2*)(feat + (size_t)s * D + lane * 4);
            acc[0] += bflo(v.x); acc[1] += bfhi(v.x);
            acc[2] += bflo(v.y); acc[3] += bfhi(v.y);
        }
    }

    int deg = end - beg;
    float invd = 1.0f / (float)(deg > 0 ? deg : 1);
    unsigned short* orow = out + (size_t)wave * D + lane * VPL;
    if constexpr (VPL == 2) {
        ushort2 o; o.x = f2bf(acc[0] * invd); o.y = f2bf(acc[1] * invd);
        *(ushort2*)orow = o;
    } else {
        ushort4 o;
        o.x = f2bf(acc[0] * invd); o.y = f2bf(acc[1] * invd);
        o.z = f2bf(acc[2] * invd); o.w = f2bf(acc[3] * invd);
        *(ushort4*)orow = o;
    }
}

// ---------------- bf16 MFMA GEMM + bias + ReLU ----------------
// MODE 0: store bf16 to Cb.  MODE 1: fused per-graph-sum (sorted gids; local
// run accumulation per thread, atomic flush per run into gsum[g*256+col]).

template <int K, int MODE>
__launch_bounds__(256)
__global__ void gemm_mfma_kernel(const unsigned short* __restrict__ A,
                                 const unsigned short* __restrict__ Wt,
                                 const float* __restrict__ bias,
                                 unsigned short* __restrict__ Cb,
                                 const int* __restrict__ gids,
                                 float* __restrict__ gsum,
                                 int N) {
    constexpr int LDS = 40;
    __shared__ unsigned short As[64 * LDS];
    __shared__ unsigned short Bs[256 * LDS];

    int tid = threadIdx.x;
    int wave = tid >> 6;
    int lane = tid & 63;
    int m = lane & 15;
    int q = lane >> 4;
    int rowBase = blockIdx.x * 64;

    f32x4 acc[4][4] = {};

    for (int kc = 0; kc < K; kc += 32) {
        {
            int r = tid >> 2;
            int seg = tid & 3;
            int gr = rowBase + r;
            uint4 v = make_uint4(0, 0, 0, 0);
            if (gr < N) v = *(const uint4*)(A + (size_t)gr * K + kc + seg * 8);
            *(uint4*)&As[r * LDS + seg * 8] = v;
        }
        #pragma unroll
        for (int it = 0; it < 4; ++it) {
            int n = (tid >> 2) + it * 64;
            int seg = tid & 3;
            uint4 v = *(const uint4*)(Wt + (size_t)n * K + kc + seg * 8);
            *(uint4*)&Bs[n * LDS + seg * 8] = v;
        }
        __syncthreads();

        bf16x8 af[4], bfr[4];
        #pragma unroll
        for (int r = 0; r < 4; ++r)
            af[r] = *(const bf16x8*)&As[(r * 16 + m) * LDS + q * 8];
        #pragma unroll
        for (int c = 0; c < 4; ++c)
            bfr[c] = *(const bf16x8*)&Bs[(wave * 64 + c * 16 + m) * LDS + q * 8];
        #pragma unroll
        for (int r = 0; r < 4; ++r)
            #pragma unroll
            for (int c = 0; c < 4; ++c)
                acc[r][c] = __builtin_amdgcn_mfma_f32_16x16x32_bf16(af[r], bfr[c], acc[r][c], 0, 0, 0);
        __syncthreads();
    }

    if constexpr (MODE == 0) {
        #pragma unroll
        for (int c = 0; c < 4; ++c) {
            int col = wave * 64 + c * 16 + m;
            float bv = bias[col];
            #pragma unroll
            for (int r = 0; r < 4; ++r) {
                #pragma unroll
                for (int reg = 0; reg < 4; ++reg) {
                    int grow = rowBase + r * 16 + q * 4 + reg;
                    if (grow < N)
                        Cb[(size_t)grow * 256 + col] = f2bf(fmaxf(acc[r][c][reg] + bv, 0.0f));
                }
            }
        }
    } else {
        // stage this block's gids (rows visited in ascending order per thread)
        int* sgid = (int*)As;
        if (tid < 64) {
            int gr = rowBase + tid;
            sgid[tid] = (gr < N) ? gids[gr] : -1;
        }
        __syncthreads();
        #pragma unroll
        for (int c = 0; c < 4; ++c) {
            int col = wave * 64 + c * 16 + m;
            float bv = bias[col];
            float partsum = 0.0f;
            int gprev = -1;
            #pragma unroll
            for (int r = 0; r < 4; ++r) {
                #pragma unroll
                for (int reg = 0; reg < 4; ++reg) {
                    int lr = r * 16 + q * 4 + reg;
                    if (rowBase + lr < N) {
                        int g = sgid[lr];
                        float o = fmaxf(acc[r][c][reg] + bv, 0.0f);
                        if (g != gprev) {
                            if (gprev >= 0) atomicAdd(&gsum[gprev * 256 + col], partsum);
                            partsum = 0.0f;
                            gprev = g;
                        }
                        partsum += o;
                    }
                }
            }
            if (gprev >= 0) atomicAdd(&gsum[gprev * 256 + col], partsum);
        }
    }
}

// ---------------- MLP head ----------------

__global__ void final_kernel(const float* __restrict__ gsum, const int* __restrict__ gstart,
                             const float* __restrict__ Wr1, const float* __restrict__ br1,
                             const float* __restrict__ Wr2, const float* __restrict__ br2,
                             float* __restrict__ out) {
    int g = blockIdx.x;
    int j = threadIdx.x;  // 128
    int c = gstart[g + 1] - gstart[g];
    float invc = 1.0f / (float)(c > 0 ? c : 1);
    const float* gs = gsum + g * 256;
    float acc = br1[j];
    for (int k = 0; k < 256; ++k)
        acc += (gs[k] * invc) * Wr1[k * 128 + j];
    float p = acc * Wr2[j];
    #pragma unroll
    for (int d = 32; d > 0; d >>= 1) p += __shfl_down(p, d, 64);
    __shared__ float ws2[2];
    if ((j & 63) == 0) ws2[j >> 6] = p;
    __syncthreads();
    if (j == 0) out[g] = ws2[0] + ws2[1] + br2[0];
}

// ---------------- launch ----------------

extern "C" void kernel_launch(void* const* d_in, const int* in_sizes, int n_in,
                              void* d_out, int out_size, void* d_ws, size_t ws_size,
                              hipStream_t stream) {
    const float* h    = (const float*)d_in[0];
    const int*   src  = (const int*)d_in[1];
    const int*   dst  = (const int*)d_in[2];
    const int*   gids = (const int*)d_in[3];
    const float* W1   = (const float*)d_in[4];
    const float* b1   = (const float*)d_in[5];
    const float* W2   = (const float*)d_in[6];
    const float* b2   = (const float*)d_in[7];
    const float* Wr1  = (const float*)d_in[8];
    const float* br1  = (const float*)d_in[9];
    const float* Wr2  = (const float*)d_in[10];
    const float* br2  = (const float*)d_in[11];

    int N = in_sizes[0] / 128;
    int E = in_sizes[1];

    // workspace
    char* w = (char*)d_ws;
    unsigned short* hb     = (unsigned short*)w;  w += (size_t)N * 128 * sizeof(unsigned short);
    unsigned short* h1b    = (unsigned short*)w;  w += (size_t)N * 256 * sizeof(unsigned short);
    unsigned short* aggOut = (unsigned short*)w;  w += (size_t)N * 256 * sizeof(unsigned short);
    int* cnt    = (int*)w;              w += (size_t)N * sizeof(int);
    int* offs   = (int*)w;              w += (size_t)(N + 1) * sizeof(int);
    int* eidx   = (int*)w;              w += (size_t)E * sizeof(int);
    int* part   = (int*)w;              w += 256 * sizeof(int);
    unsigned short* Wt1 = (unsigned short*)w;  w += 256 * 128 * sizeof(unsigned short);
    unsigned short* Wt2 = (unsigned short*)w;  w += 256 * 256 * sizeof(unsigned short);
    float* gsum = (float*)w;            w += (size_t)NUM_GRAPHS * 256 * sizeof(float);
    int* gstart = (int*)w;              w += (size_t)(NUM_GRAPHS + 1) * sizeof(int);

    // one cooperative prep kernel: zero + count + scan + scatter + gstart +
    // weight transpose/cast + h cast  (grid MUST stay 256x256: 1 block/CU)
    {
        void* args[] = {(void*)&src, (void*)&dst, (void*)&gids, (void*)&h,
                        (void*)&W1, (void*)&W2, (void*)&cnt, (void*)&offs,
                        (void*)&eidx, (void*)&part, (void*)&gstart, (void*)&hb,
                        (void*)&Wt1, (void*)&Wt2, (void*)&gsum, (void*)&N, (void*)&E};
        hipLaunchCooperativeKernel((const void*)prep_kernel, dim3(256), dim3(256),
                                   args, 0, stream);
    }

    // layer 1
    agg_mean_bf16_kernel<128><<<(N + 3) / 4, 256, 0, stream>>>(hb, offs, eidx, aggOut, N);
    gemm_mfma_kernel<128, 0><<<(N + 63) / 64, 256, 0, stream>>>(aggOut, Wt1, b1, h1b, nullptr, nullptr, N);

    // layer 2 (readout fused into GEMM epilogue)
    agg_mean_bf16_kernel<256><<<(N + 3) / 4, 256, 0, stream>>>(h1b, offs, eidx, aggOut, N);
    gemm_mfma_kernel<256, 1><<<(N + 63) / 64, 256, 0, stream>>>(aggOut, Wt2, b2, nullptr, gids, gsum, N);

    final_kernel<<<NUM_GRAPHS, 128, 0, stream>>>(gsum, gstart, Wr1, br1, Wr2, br2, (float*)d_out);
}